// Round 3
// baseline (482.842 us; speedup 1.0000x reference)
//
#include <hip/hip_runtime.h>
#include <hip/hip_bf16.h>
#include <cstddef>
#include <cstdint>

static constexpr int BSZ  = 8;
static constexpr int NN   = 512;
static constexpr int FF   = 512;
static constexpr int RR   = 16;
static constexpr int TWOF = 1024;

typedef __attribute__((ext_vector_type(8))) short short8;   // 8 bf16 in 4 VGPRs
typedef __attribute__((ext_vector_type(4))) float f32x4;

__device__ __forceinline__ ushort bf16_bits(float v) {
    union { __hip_bfloat16 h; ushort u; } cvt;
    cvt.h = __float2bfloat16(v);
    return cvt.u;
}

// ---------------------------------------------------------------------------
// Workspace layout (byte offsets, 256B aligned)
// ---------------------------------------------------------------------------
static constexpr size_t OFF_MQ     = 32768;     // f32 [8][512]
static constexpr size_t OFF_MK     = 49152;     // f32 [8][512]
static constexpr size_t OFF_SQ     = 65536;     // f32 [8][512][16]
static constexpr size_t OFF_SK     = 327680;    // f32 [8][512][16]
static constexpr size_t OFF_WQET   = 589824;    // bf16 [8][16][1024]
static constexpr size_t OFF_WKET   = 851968;    // bf16 [8][16][1024]
static constexpr size_t OFF_ATTN   = 1114112;   // bf16 [8][512][512]
static constexpr size_t OFF_XBF    = 5308416;   // bf16 [8][512][512]
static constexpr size_t OFF_XTBF   = 9502720;   // bf16 [8][512][512]  (x^T per b)
static constexpr size_t OFF_XORIBF = 13697024;  // bf16 [8][512][512]
static constexpr size_t OFF_NEWXBF = 17891328;  // bf16 [8][512][512]
static constexpr size_t OFF_WUT    = 22085632;  // bf16 [512][1024]    (Wu^T)

// ---------------------------------------------------------------------------
// Fused prep kernel, block-range dispatch, 256 threads:
//   blocks [0,1024):     x_ori -> xori_bf (8 f32 -> bf16 per thread)
//   blocks [1024,3072):  x -> x_bf + xT_bf (32x32 transpose tiles)
//   blocks [3072,3584):  Wu -> WuT_bf (32x32 transpose tiles)
//   blocks [3584,3592):  full m-chain per batch: mq/mk = (elu(c@Wfc)@Wdc)@{Wqc,Wkc}
// ---------------------------------------------------------------------------
__global__ __launch_bounds__(256) void k_prep(
    const float* __restrict__ x_ori, const float* __restrict__ x,
    const float* __restrict__ c,
    const float* __restrict__ Wfc, const float* __restrict__ Wdc,
    const float* __restrict__ Wqc, const float* __restrict__ Wkc,
    const float* __restrict__ Wu,
    ushort* __restrict__ xori_bf, ushort* __restrict__ x_bf,
    ushort* __restrict__ xT_bf, ushort* __restrict__ WuT,
    float* __restrict__ mq, float* __restrict__ mk)
{
    int blk = blockIdx.x;
    int t = threadIdx.x;
    if (blk < 1024) {
        // ---- cvt x_ori -> bf16 ----
        int idx = blk * 256 + t;
        float4 a = ((const float4*)x_ori)[idx * 2];
        float4 b = ((const float4*)x_ori)[idx * 2 + 1];
        uint4 s;
        s.x = (uint)bf16_bits(a.x) | ((uint)bf16_bits(a.y) << 16);
        s.y = (uint)bf16_bits(a.z) | ((uint)bf16_bits(a.w) << 16);
        s.z = (uint)bf16_bits(b.x) | ((uint)bf16_bits(b.y) << 16);
        s.w = (uint)bf16_bits(b.z) | ((uint)bf16_bits(b.w) << 16);
        ((uint4*)xori_bf)[idx] = s;
    } else if (blk < 3072) {
        // ---- x -> x_bf + xT_bf ----
        __shared__ float tile[32][33];
        int bb = blk - 1024;
        int f0 = (bb & 15) * 32, i0 = ((bb >> 4) & 15) * 32, b = bb >> 8;
        int cc = t & 31, r0 = t >> 5;  // r0 in 0..7
#pragma unroll
        for (int rr = 0; rr < 32; rr += 8) {
            int i = i0 + r0 + rr;
            float v = x[((size_t)b * NN + i) * FF + f0 + cc];
            tile[r0 + rr][cc] = v;
            x_bf[((size_t)b * NN + i) * FF + f0 + cc] = bf16_bits(v);
        }
        __syncthreads();
#pragma unroll
        for (int rr = 0; rr < 32; rr += 8) {
            int f = f0 + r0 + rr;
            xT_bf[((size_t)b * FF + f) * NN + i0 + cc] = bf16_bits(tile[cc][r0 + rr]);
        }
    } else if (blk < 3584) {
        // ---- Wu [1024][512] -> WuT [512][1024] ----
        __shared__ float tile2[32][33];
        int bb = blk - 3072;
        int f0 = (bb & 31) * 32, o0 = (bb >> 5) * 32;
        int cc = t & 31, r0 = t >> 5;
#pragma unroll
        for (int rr = 0; rr < 32; rr += 8)
            tile2[r0 + rr][cc] = Wu[(size_t)(f0 + r0 + rr) * FF + o0 + cc];
        __syncthreads();
#pragma unroll
        for (int rr = 0; rr < 32; rr += 8)
            WuT[(size_t)(o0 + r0 + rr) * TWOF + f0 + cc] = bf16_bits(tile2[cc][r0 + rr]);
    } else {
        // ---- m-chain, one block per batch ----
        __shared__ float cv[512];
        __shared__ float tv[512];
        __shared__ float mv[512];
        int b = blk - 3584;
        cv[t] = c[(size_t)b * FF + t];
        cv[t + 256] = c[(size_t)b * FF + t + 256];
        __syncthreads();
        // stage 1: tv = elu(cv @ Wfc)
        {
            float a1 = 0.f, a2 = 0.f;
#pragma unroll 4
            for (int k = 0; k < 512; ++k) {
                float v = cv[k];
                a1 = fmaf(v, Wfc[(size_t)k * FF + t], a1);
                a2 = fmaf(v, Wfc[(size_t)k * FF + t + 256], a2);
            }
            tv[t] = (a1 > 0.f) ? a1 : expm1f(a1);
            tv[t + 256] = (a2 > 0.f) ? a2 : expm1f(a2);
        }
        __syncthreads();
        // stage 2: mv = tv @ Wdc
        {
            float a1 = 0.f, a2 = 0.f;
#pragma unroll 4
            for (int k = 0; k < 512; ++k) {
                float v = tv[k];
                a1 = fmaf(v, Wdc[(size_t)k * FF + t], a1);
                a2 = fmaf(v, Wdc[(size_t)k * FF + t + 256], a2);
            }
            mv[t] = a1;
            mv[t + 256] = a2;
        }
        __syncthreads();
        // stage 3: mq = mv @ Wqc ; mk = mv @ Wkc
        {
            float q1 = 0.f, q2 = 0.f, k1 = 0.f, k2 = 0.f;
#pragma unroll 4
            for (int k = 0; k < 512; ++k) {
                float v = mv[k];
                q1 = fmaf(v, Wqc[(size_t)k * FF + t], q1);
                q2 = fmaf(v, Wqc[(size_t)k * FF + t + 256], q2);
                k1 = fmaf(v, Wkc[(size_t)k * FF + t], k1);
                k2 = fmaf(v, Wkc[(size_t)k * FF + t + 256], k2);
            }
            mq[(size_t)b * FF + t] = q1;
            mq[(size_t)b * FF + t + 256] = q2;
            mk[(size_t)b * FF + t] = k1;
            mk[(size_t)b * FF + t + 256] = k2;
        }
    }
}

// ---------------------------------------------------------------------------
// W_eff^T[b,r,k] = sum_f W[k,f] * mvec[b,f] * Wa[waRowOff+f, r]  (bf16 out)
// grid (16 kchunks, 8 b, 2 {q,k}), block 256
// ---------------------------------------------------------------------------
__global__ __launch_bounds__(256) void k_weff(const float* __restrict__ Wqv,
                                              const float* __restrict__ Wkv,
                                              const float* __restrict__ Wa,
                                              const float* __restrict__ mqv,
                                              const float* __restrict__ mkv,
                                              ushort* __restrict__ WqEt,
                                              ushort* __restrict__ WkEt) {
    int z = blockIdx.z;
    const float* W = z ? Wkv : Wqv;
    const float* mvec = z ? mkv : mqv;
    ushort* WeffT = z ? WkEt : WqEt;
    int waRowOff = z ? FF : 0;

    __shared__ float4 wa4[FF * 4];  // [f][r4] scaled Wa, 32 KiB
    int tid = threadIdx.x;
    int b = blockIdx.y;
    const float* mv = mvec + (size_t)b * FF;
#pragma unroll
    for (int qq = 0; qq < 8; ++qq) {
        int idx = tid + qq * 256;
        int f = idx >> 2, rq = idx & 3;
        float4 w = *reinterpret_cast<const float4*>(Wa + (size_t)(waRowOff + f) * RR + rq * 4);
        float s = mv[f];
        float4 o;
        o.x = w.x * s; o.y = w.y * s; o.z = w.z * s; o.w = w.w * s;
        wa4[idx] = o;
    }
    __syncthreads();
    int k_l = tid >> 2, r4 = tid & 3;
    int k = blockIdx.x * 64 + k_l;
    const float* Wrow = W + (size_t)k * FF;
    float4 acc = {0.f, 0.f, 0.f, 0.f};
#pragma unroll 4
    for (int f = 0; f < FF; ++f) {
        float w = Wrow[f];
        float4 v = wa4[f * 4 + r4];
        acc.x = fmaf(w, v.x, acc.x);
        acc.y = fmaf(w, v.y, acc.y);
        acc.z = fmaf(w, v.z, acc.z);
        acc.w = fmaf(w, v.w, acc.w);
    }
    WeffT[((size_t)b * RR + r4 * 4 + 0) * TWOF + k] = bf16_bits(acc.x);
    WeffT[((size_t)b * RR + r4 * 4 + 1) * TWOF + k] = bf16_bits(acc.y);
    WeffT[((size_t)b * RR + r4 * 4 + 2) * TWOF + k] = bf16_bits(acc.z);
    WeffT[((size_t)b * RR + r4 * 4 + 3) * TWOF + k] = bf16_bits(acc.w);
}

// ---------------------------------------------------------------------------
// sq/sk via MFMA, LDS-free (both fragments are direct 16-B global loads).
// grid (16 m-tiles of 32, 8 b), block 256 = 4 waves:
//   wave w: sub-tile (w&1), output (w>>1 ? sk : sq)
// ---------------------------------------------------------------------------
__global__ __launch_bounds__(256) void k_sqsk(const ushort* __restrict__ x_bf,
                                              const ushort* __restrict__ xori_bf,
                                              const ushort* __restrict__ WqEt,
                                              const ushort* __restrict__ WkEt,
                                              float* __restrict__ sq,
                                              float* __restrict__ sk) {
    int t = threadIdx.x;
    int b = blockIdx.y;
    int m0 = blockIdx.x * 32;
    int lane = t & 63, w = t >> 6;
    int sub = w & 1, isK = w >> 1;
    int m_l = lane & 15, q = lane >> 4;
    int row = m0 + sub * 16 + m_l;
    const ushort* Bt = (isK ? WkEt : WqEt) + ((size_t)b * RR + m_l) * TWOF;
    f32x4 acc = {0.f, 0.f, 0.f, 0.f};
#pragma unroll
    for (int k0 = 0; k0 < TWOF; k0 += 32) {
        const ushort* src = (k0 < FF) ? x_bf : xori_bf;
        int kc = k0 & (FF - 1);
        short8 af = *(const short8*)(src + ((size_t)b * NN + row) * FF + kc + q * 8);
        short8 bf = *(const short8*)(Bt + k0 + q * 8);
        acc = __builtin_amdgcn_mfma_f32_16x16x32_bf16(af, bf, acc, 0, 0, 0);
    }
    float* dst = isK ? sk : sq;
#pragma unroll
    for (int r = 0; r < 4; ++r) {
        int i = m0 + sub * 16 + q * 4 + r;
        dst[((size_t)b * NN + i) * RR + m_l] = acc[r];
    }
}

// ---------------------------------------------------------------------------
// Fused scores + mask + softmax -> attn_bf.  grid (512 i, 8 b), block 256.
// ---------------------------------------------------------------------------
__global__ __launch_bounds__(256) void k_attn(const int* __restrict__ adj,
                                              const float* __restrict__ sq,
                                              const float* __restrict__ sk,
                                              ushort* __restrict__ attn_bf) {
    int t = threadIdx.x;
    int i = blockIdx.x;
    int b = blockIdx.y;
    __shared__ float sqv_s[RR];
    __shared__ float redmax[4];
    __shared__ float redsum[4];
    __shared__ float bc_max;
    __shared__ float bc_sum;
    if (t < RR) sqv_s[t] = sq[((size_t)b * NN + i) * RR + t];
    __syncthreads();
    float sv[RR];
#pragma unroll
    for (int r = 0; r < RR; ++r) sv[r] = sqv_s[r];

    float z[2];
#pragma unroll
    for (int jj = 0; jj < 2; ++jj) {
        int j = t + jj * 256;
        size_t base = ((size_t)(b * NN + i) * NN + j) * RR;
        const int4* ap = reinterpret_cast<const int4*>(adj + base);
        int4 a0 = ap[0], a1 = ap[1], a2 = ap[2], a3 = ap[3];
        const float4* kp = reinterpret_cast<const float4*>(sk + ((size_t)b * NN + j) * RR);
        float4 s0 = kp[0], s1 = kp[1], s2 = kp[2], s3 = kp[3];
        int sum_adj = a0.x + a0.y + a0.z + a0.w + a1.x + a1.y + a1.z + a1.w +
                      a2.x + a2.y + a2.z + a2.w + a3.x + a3.y + a3.z + a3.w;
        float ssum = 0.f;
#define LR_TERM(SVAL, AVAL, RIDX)                                   \
        { float v_ = sv[RIDX] + (SVAL);                             \
          v_ = fmaxf(v_, 0.2f * v_);                                \
          ssum = fmaf(v_, (float)(AVAL), ssum); }
        LR_TERM(s0.x, a0.x, 0)  LR_TERM(s0.y, a0.y, 1)
        LR_TERM(s0.z, a0.z, 2)  LR_TERM(s0.w, a0.w, 3)
        LR_TERM(s1.x, a1.x, 4)  LR_TERM(s1.y, a1.y, 5)
        LR_TERM(s1.z, a1.z, 6)  LR_TERM(s1.w, a1.w, 7)
        LR_TERM(s2.x, a2.x, 8)  LR_TERM(s2.y, a2.y, 9)
        LR_TERM(s2.z, a2.z, 10) LR_TERM(s2.w, a2.w, 11)
        LR_TERM(s3.x, a3.x, 12) LR_TERM(s3.y, a3.y, 13)
        LR_TERM(s3.z, a3.z, 14) LR_TERM(s3.w, a3.w, 15)
#undef LR_TERM
        z[jj] = (sum_adj > 0) ? ssum : -9e15f;
    }

    int wv = t >> 6, ln = t & 63;
    float lm = fmaxf(z[0], z[1]);
    for (int off = 32; off; off >>= 1) lm = fmaxf(lm, __shfl_xor(lm, off, 64));
    if (ln == 0) redmax[wv] = lm;
    __syncthreads();
    if (t == 0) bc_max = fmaxf(fmaxf(redmax[0], redmax[1]), fmaxf(redmax[2], redmax[3]));
    __syncthreads();
    float mx = bc_max;
    float e0 = __expf(z[0] - mx);
    float e1 = __expf(z[1] - mx);
    float ls = e0 + e1;
    for (int off = 32; off; off >>= 1) ls += __shfl_xor(ls, off, 64);
    if (ln == 0) redsum[wv] = ls;
    __syncthreads();
    if (t == 0) bc_sum = redsum[0] + redsum[1] + redsum[2] + redsum[3];
    __syncthreads();
    float inv = 1.f / bc_sum;
    ushort* outp = attn_bf + (size_t)(b * NN + i) * NN;
    outp[t] = bf16_bits(e0 * inv);
    outp[t + 256] = bf16_bits(e1 * inv);
}

// ---------------------------------------------------------------------------
// bf16 MFMA GEMM: C[b] (MxN) = A[b] (MxK row-major, split at k=512) @ BT^T
// 64x64 tile; two BK=32 stages per barrier-pair (dual LDS buffers).
// block 256 = 4 waves, wave w computes rows w*16..+16 x all 64 cols.
// grid (N/64, M/64, 8)
// ---------------------------------------------------------------------------
__global__ __launch_bounds__(256) void k_gemm(const ushort* __restrict__ A1, size_t sA1,
                                              const ushort* __restrict__ A2, size_t sA2,
                                              const ushort* __restrict__ BT, size_t sBT,
                                              float* __restrict__ Cf,
                                              ushort* __restrict__ Cb, size_t sC,
                                              int K, int ldBT) {
    __shared__ ushort As[2][64 * 40];  // stride 40 ushort = 80 B (16B-aligned rows)
    __shared__ ushort Bs[2][64 * 40];
    int t = threadIdx.x;
    int n0 = blockIdx.x * 64, m0 = blockIdx.y * 64, b = blockIdx.z;
    int row = t >> 2, c8 = (t & 3) * 8;
    int lane = t & 63, w = t >> 6;
    int m_l = lane & 15, q = lane >> 4;
    f32x4 acc[4] = {{0.f,0.f,0.f,0.f},{0.f,0.f,0.f,0.f},{0.f,0.f,0.f,0.f},{0.f,0.f,0.f,0.f}};
    const ushort* BTb = BT + (size_t)b * sBT;
    for (int k0 = 0; k0 < K; k0 += 64) {
#pragma unroll
        for (int h = 0; h < 2; ++h) {
            int kk = k0 + h * 32;
            const ushort* Aab; int kc;
            if (kk < FF) { Aab = A1 + (size_t)b * sA1; kc = kk; }
            else         { Aab = A2 + (size_t)b * sA2; kc = kk - FF; }
            uint4 av = *(const uint4*)(Aab + (size_t)(m0 + row) * FF + kc + c8);
            uint4 bv = *(const uint4*)(BTb + (size_t)(n0 + row) * ldBT + kk + c8);
            *(uint4*)(&As[h][row * 40 + c8]) = av;
            *(uint4*)(&Bs[h][row * 40 + c8]) = bv;
        }
        __syncthreads();
#pragma unroll
        for (int h = 0; h < 2; ++h) {
            short8 af = *(const short8*)(&As[h][(w * 16 + m_l) * 40 + q * 8]);
#pragma unroll
            for (int nb = 0; nb < 4; ++nb) {
                short8 bfr = *(const short8*)(&Bs[h][(nb * 16 + m_l) * 40 + q * 8]);
                acc[nb] = __builtin_amdgcn_mfma_f32_16x16x32_bf16(af, bfr, acc[nb], 0, 0, 0);
            }
        }
        __syncthreads();
    }
#pragma unroll
    for (int nb = 0; nb < 4; ++nb) {
#pragma unroll
        for (int r = 0; r < 4; ++r) {
            int mi = m0 + w * 16 + q * 4 + r;
            int ni = n0 + nb * 16 + m_l;
            float v = acc[nb][r];
            if (Cb) Cb[(size_t)b * sC + (size_t)mi * FF + ni] = bf16_bits(v);
            else    Cf[(size_t)b * sC + (size_t)mi * FF + ni] = v;
        }
    }
}

// ---------------------------------------------------------------------------
// Launch
// ---------------------------------------------------------------------------
extern "C" void kernel_launch(void* const* d_in, const int* in_sizes, int n_in,
                              void* d_out, int out_size, void* d_ws, size_t ws_size,
                              hipStream_t stream) {
    const float* x_ori = (const float*)d_in[0];
    const float* x     = (const float*)d_in[1];
    const float* c     = (const float*)d_in[2];
    const int*   adj   = (const int*)d_in[3];
    const float* Wfc   = (const float*)d_in[4];
    const float* Wdc   = (const float*)d_in[5];
    const float* Wqv   = (const float*)d_in[6];
    const float* Wkv   = (const float*)d_in[7];
    const float* Wqc   = (const float*)d_in[8];
    const float* Wkc   = (const float*)d_in[9];
    const float* Wa    = (const float*)d_in[10];
    const float* Wu    = (const float*)d_in[11];
    float* out = (float*)d_out;

    char* ws = (char*)d_ws;
    float*  mq      = (float*)(ws + OFF_MQ);
    float*  mk      = (float*)(ws + OFF_MK);
    float*  sq      = (float*)(ws + OFF_SQ);
    float*  sk      = (float*)(ws + OFF_SK);
    ushort* WqEt    = (ushort*)(ws + OFF_WQET);
    ushort* WkEt    = (ushort*)(ws + OFF_WKET);
    ushort* attn_bf = (ushort*)(ws + OFF_ATTN);
    ushort* x_bf    = (ushort*)(ws + OFF_XBF);
    ushort* xT_bf   = (ushort*)(ws + OFF_XTBF);
    ushort* xori_bf = (ushort*)(ws + OFF_XORIBF);
    ushort* newx_bf = (ushort*)(ws + OFF_NEWXBF);
    ushort* WuT     = (ushort*)(ws + OFF_WUT);

    dim3 blk(256);

    // 1) all conversions/transposes + m-chain in one launch
    k_prep<<<dim3(3592), blk, 0, stream>>>(x_ori, x, c, Wfc, Wdc, Wqc, Wkc, Wu,
                                           xori_bf, x_bf, xT_bf, WuT, mq, mk);

    // 2) effective low-rank weights (q and k via blockIdx.z)
    k_weff<<<dim3(16, BSZ, 2), blk, 0, stream>>>(Wqv, Wkv, Wa, mq, mk, WqEt, WkEt);

    // 3) sq / sk via LDS-free MFMA
    k_sqsk<<<dim3(16, BSZ), blk, 0, stream>>>(x_bf, xori_bf, WqEt, WkEt, sq, sk);

    // 4) scores + mask + softmax -> attn (bf16)
    k_attn<<<dim3(NN, BSZ), blk, 0, stream>>>(adj, sq, sk, attn_bf);

    // 5) new_x = attn @ x
    k_gemm<<<dim3(8, 8, BSZ), blk, 0, stream>>>(
        attn_bf, (size_t)NN * NN, attn_bf, (size_t)NN * NN,
        xT_bf, (size_t)FF * NN, nullptr, newx_bf, (size_t)NN * FF, FF, NN);

    // 6) out = [x | new_x] @ Wu
    k_gemm<<<dim3(8, 8, BSZ), blk, 0, stream>>>(
        x_bf, (size_t)NN * FF, newx_bf, (size_t)NN * FF,
        WuT, (size_t)0, out, nullptr, (size_t)NN * FF, TWOF, TWOF);
}

// Round 4
// 308.159 us; speedup vs baseline: 1.5669x; 1.5669x over previous
//
#include <hip/hip_runtime.h>
#include <hip/hip_bf16.h>
#include <cstddef>
#include <cstdint>

static constexpr int BSZ  = 8;
static constexpr int NN   = 512;
static constexpr int FF   = 512;
static constexpr int RR   = 16;
static constexpr int TWOF = 1024;

typedef __attribute__((ext_vector_type(8))) short short8;   // 8 bf16 in 4 VGPRs
typedef __attribute__((ext_vector_type(4))) float f32x4;

__device__ __forceinline__ ushort bf16_bits(float v) {
    union { __hip_bfloat16 h; ushort u; } cvt;
    cvt.h = __float2bfloat16(v);
    return cvt.u;
}

// ---------------------------------------------------------------------------
// Workspace layout (byte offsets, 256B aligned)
// ---------------------------------------------------------------------------
static constexpr size_t OFF_TB     = 0;         // f32 [8][512]
static constexpr size_t OFF_MB     = 16384;     // f32 [8][512]
static constexpr size_t OFF_MQ     = 32768;     // f32 [8][512]
static constexpr size_t OFF_MK     = 49152;     // f32 [8][512]
static constexpr size_t OFF_SQ     = 65536;     // f32 [8][512][16]
static constexpr size_t OFF_SK     = 327680;    // f32 [8][512][16]
static constexpr size_t OFF_WQET   = 589824;    // bf16 [8][16][1024]
static constexpr size_t OFF_WKET   = 851968;    // bf16 [8][16][1024]
static constexpr size_t OFF_ATTN   = 1114112;   // bf16 [8][512][512]
static constexpr size_t OFF_XBF    = 5308416;   // bf16 [8][512][512]
static constexpr size_t OFF_XTBF   = 9502720;   // bf16 [8][512][512]  (x^T per b)
static constexpr size_t OFF_XORIBF = 13697024;  // bf16 [8][512][512]
static constexpr size_t OFF_NEWXBF = 17891328;  // bf16 [8][512][512]
static constexpr size_t OFF_WUT    = 22085632;  // bf16 [512][1024]    (Wu^T)

// ---------------------------------------------------------------------------
// Fused prep kernel (uniform-parallelism branches ONLY — m-chain split out;
// round-3 lesson: 8-block branch serialized the whole 3584-block kernel):
//   blocks [0,1024):     x_ori -> xori_bf
//   blocks [1024,3072):  x -> x_bf + xT_bf (32x32 transpose tiles)
//   blocks [3072,3584):  Wu -> WuT_bf
// ---------------------------------------------------------------------------
__global__ __launch_bounds__(256) void k_prep(
    const float* __restrict__ x_ori, const float* __restrict__ x,
    const float* __restrict__ Wu,
    ushort* __restrict__ xori_bf, ushort* __restrict__ x_bf,
    ushort* __restrict__ xT_bf, ushort* __restrict__ WuT)
{
    int blk = blockIdx.x;
    int t = threadIdx.x;
    if (blk < 1024) {
        int idx = blk * 256 + t;
        float4 a = ((const float4*)x_ori)[idx * 2];
        float4 b = ((const float4*)x_ori)[idx * 2 + 1];
        uint4 s;
        s.x = (uint)bf16_bits(a.x) | ((uint)bf16_bits(a.y) << 16);
        s.y = (uint)bf16_bits(a.z) | ((uint)bf16_bits(a.w) << 16);
        s.z = (uint)bf16_bits(b.x) | ((uint)bf16_bits(b.y) << 16);
        s.w = (uint)bf16_bits(b.z) | ((uint)bf16_bits(b.w) << 16);
        ((uint4*)xori_bf)[idx] = s;
    } else if (blk < 3072) {
        __shared__ float tile[32][33];
        int bb = blk - 1024;
        int f0 = (bb & 15) * 32, i0 = ((bb >> 4) & 15) * 32, b = bb >> 8;
        int cc = t & 31, r0 = t >> 5;  // r0 in 0..7
#pragma unroll
        for (int rr = 0; rr < 32; rr += 8) {
            int i = i0 + r0 + rr;
            float v = x[((size_t)b * NN + i) * FF + f0 + cc];
            tile[r0 + rr][cc] = v;
            x_bf[((size_t)b * NN + i) * FF + f0 + cc] = bf16_bits(v);
        }
        __syncthreads();
#pragma unroll
        for (int rr = 0; rr < 32; rr += 8) {
            int f = f0 + r0 + rr;
            xT_bf[((size_t)b * FF + f) * NN + i0 + cc] = bf16_bits(tile[cc][r0 + rr]);
        }
    } else {
        __shared__ float tile2[32][33];
        int bb = blk - 3072;
        int f0 = (bb & 31) * 32, o0 = (bb >> 5) * 32;
        int cc = t & 31, r0 = t >> 5;
#pragma unroll
        for (int rr = 0; rr < 32; rr += 8)
            tile2[r0 + rr][cc] = Wu[(size_t)(f0 + r0 + rr) * FF + o0 + cc];
        __syncthreads();
#pragma unroll
        for (int rr = 0; rr < 32; rr += 8)
            WuT[(size_t)(o0 + r0 + rr) * TWOF + f0 + cc] = bf16_bits(tile2[cc][r0 + rr]);
    }
}

// ---------------------------------------------------------------------------
// Batched GEMV: vout[b,f] = act(vin[b,:] @ W[:,f])
// grid (16 fb, 8 b), block 256 = (32 f, 8 kq) — 128 blocks, 8-way k-split
// ---------------------------------------------------------------------------
__global__ __launch_bounds__(256) void k_matvec(const float* __restrict__ vin,
                                                const float* __restrict__ W,
                                                float* __restrict__ vout,
                                                int elu_out) {
    __shared__ float red[8][32];
    int b = blockIdx.y;
    int f0 = blockIdx.x * 32;
    int t = threadIdx.x;
    int f = t & 31, kq = t >> 5;
    const float* vb = vin + (size_t)b * FF;
    float acc = 0.f;
    int ks = kq * 64;
#pragma unroll 8
    for (int k = ks; k < ks + 64; ++k)
        acc = fmaf(vb[k], W[(size_t)k * FF + f0 + f], acc);
    red[kq][f] = acc;
    __syncthreads();
    if (kq == 0) {
        acc += red[1][f] + red[2][f] + red[3][f] + red[4][f] +
               red[5][f] + red[6][f] + red[7][f];
        if (elu_out) acc = (acc > 0.f) ? acc : expm1f(acc);
        vout[(size_t)b * FF + f0 + f] = acc;
    }
}

// mq = m @ Wqc ; mk = m @ Wkc
__global__ __launch_bounds__(256) void k_mqk(const float* __restrict__ m,
                                             const float* __restrict__ Wqc,
                                             const float* __restrict__ Wkc,
                                             float* __restrict__ mq,
                                             float* __restrict__ mk) {
    __shared__ float redq[8][32];
    __shared__ float redk[8][32];
    int b = blockIdx.y;
    int f0 = blockIdx.x * 32;
    int t = threadIdx.x;
    int f = t & 31, kq = t >> 5;
    const float* mb = m + (size_t)b * FF;
    float aq = 0.f, ak = 0.f;
    int ks = kq * 64;
#pragma unroll 8
    for (int k = ks; k < ks + 64; ++k) {
        float mv = mb[k];
        aq = fmaf(mv, Wqc[(size_t)k * FF + f0 + f], aq);
        ak = fmaf(mv, Wkc[(size_t)k * FF + f0 + f], ak);
    }
    redq[kq][f] = aq;
    redk[kq][f] = ak;
    __syncthreads();
    if (kq == 0) {
        aq += redq[1][f] + redq[2][f] + redq[3][f] + redq[4][f] +
              redq[5][f] + redq[6][f] + redq[7][f];
        ak += redk[1][f] + redk[2][f] + redk[3][f] + redk[4][f] +
              redk[5][f] + redk[6][f] + redk[7][f];
        mq[(size_t)b * FF + f0 + f] = aq;
        mk[(size_t)b * FF + f0 + f] = ak;
    }
}

// ---------------------------------------------------------------------------
// W_eff^T[b,r,k] = sum_f W[k,f] * mvec[b,f] * Wa[waRowOff+f, r]  (bf16 out)
// grid (16 kchunks, 8 b, 2 {q,k}), block 256.  f-loop vectorized x4.
// ---------------------------------------------------------------------------
__global__ __launch_bounds__(256) void k_weff(const float* __restrict__ Wqv,
                                              const float* __restrict__ Wkv,
                                              const float* __restrict__ Wa,
                                              const float* __restrict__ mqv,
                                              const float* __restrict__ mkv,
                                              ushort* __restrict__ WqEt,
                                              ushort* __restrict__ WkEt) {
    int z = blockIdx.z;
    const float* W = z ? Wkv : Wqv;
    const float* mvec = z ? mkv : mqv;
    ushort* WeffT = z ? WkEt : WqEt;
    int waRowOff = z ? FF : 0;

    __shared__ float4 wa4[FF * 4];  // [f][r4] scaled Wa, 32 KiB
    int tid = threadIdx.x;
    int b = blockIdx.y;
    const float* mv = mvec + (size_t)b * FF;
#pragma unroll
    for (int qq = 0; qq < 8; ++qq) {
        int idx = tid + qq * 256;
        int f = idx >> 2, rq = idx & 3;
        float4 w = *reinterpret_cast<const float4*>(Wa + (size_t)(waRowOff + f) * RR + rq * 4);
        float s = mv[f];
        float4 o;
        o.x = w.x * s; o.y = w.y * s; o.z = w.z * s; o.w = w.w * s;
        wa4[idx] = o;
    }
    __syncthreads();
    int k_l = tid >> 2, r4 = tid & 3;
    int k = blockIdx.x * 64 + k_l;
    const float4* Wrow4 = reinterpret_cast<const float4*>(W + (size_t)k * FF);
    float4 acc = {0.f, 0.f, 0.f, 0.f};
#pragma unroll 4
    for (int f4 = 0; f4 < FF / 4; ++f4) {
        float4 w = Wrow4[f4];
        float4 v0 = wa4[(f4 * 4 + 0) * 4 + r4];
        float4 v1 = wa4[(f4 * 4 + 1) * 4 + r4];
        float4 v2 = wa4[(f4 * 4 + 2) * 4 + r4];
        float4 v3 = wa4[(f4 * 4 + 3) * 4 + r4];
        acc.x = fmaf(w.x, v0.x, acc.x); acc.y = fmaf(w.x, v0.y, acc.y);
        acc.z = fmaf(w.x, v0.z, acc.z); acc.w = fmaf(w.x, v0.w, acc.w);
        acc.x = fmaf(w.y, v1.x, acc.x); acc.y = fmaf(w.y, v1.y, acc.y);
        acc.z = fmaf(w.y, v1.z, acc.z); acc.w = fmaf(w.y, v1.w, acc.w);
        acc.x = fmaf(w.z, v2.x, acc.x); acc.y = fmaf(w.z, v2.y, acc.y);
        acc.z = fmaf(w.z, v2.z, acc.z); acc.w = fmaf(w.z, v2.w, acc.w);
        acc.x = fmaf(w.w, v3.x, acc.x); acc.y = fmaf(w.w, v3.y, acc.y);
        acc.z = fmaf(w.w, v3.z, acc.z); acc.w = fmaf(w.w, v3.w, acc.w);
    }
    WeffT[((size_t)b * RR + r4 * 4 + 0) * TWOF + k] = bf16_bits(acc.x);
    WeffT[((size_t)b * RR + r4 * 4 + 1) * TWOF + k] = bf16_bits(acc.y);
    WeffT[((size_t)b * RR + r4 * 4 + 2) * TWOF + k] = bf16_bits(acc.z);
    WeffT[((size_t)b * RR + r4 * 4 + 3) * TWOF + k] = bf16_bits(acc.w);
}

// ---------------------------------------------------------------------------
// sq/sk via MFMA, LDS-free. grid (16 m-tiles of 32, 8 b), block 256 = 4 waves
// ---------------------------------------------------------------------------
__global__ __launch_bounds__(256) void k_sqsk(const ushort* __restrict__ x_bf,
                                              const ushort* __restrict__ xori_bf,
                                              const ushort* __restrict__ WqEt,
                                              const ushort* __restrict__ WkEt,
                                              float* __restrict__ sq,
                                              float* __restrict__ sk) {
    int t = threadIdx.x;
    int b = blockIdx.y;
    int m0 = blockIdx.x * 32;
    int lane = t & 63, w = t >> 6;
    int sub = w & 1, isK = w >> 1;
    int m_l = lane & 15, q = lane >> 4;
    int row = m0 + sub * 16 + m_l;
    const ushort* Bt = (isK ? WkEt : WqEt) + ((size_t)b * RR + m_l) * TWOF;
    f32x4 acc = {0.f, 0.f, 0.f, 0.f};
#pragma unroll
    for (int k0 = 0; k0 < TWOF; k0 += 32) {
        const ushort* src = (k0 < FF) ? x_bf : xori_bf;
        int kc = k0 & (FF - 1);
        short8 af = *(const short8*)(src + ((size_t)b * NN + row) * FF + kc + q * 8);
        short8 bf = *(const short8*)(Bt + k0 + q * 8);
        acc = __builtin_amdgcn_mfma_f32_16x16x32_bf16(af, bf, acc, 0, 0, 0);
    }
    float* dst = isK ? sk : sq;
#pragma unroll
    for (int r = 0; r < 4; ++r) {
        int i = m0 + sub * 16 + q * 4 + r;
        dst[((size_t)b * NN + i) * RR + m_l] = acc[r];
    }
}

// ---------------------------------------------------------------------------
// Fused scores + mask + softmax -> attn_bf.  grid (512 i, 8 b), block 256.
// ---------------------------------------------------------------------------
__global__ __launch_bounds__(256) void k_attn(const int* __restrict__ adj,
                                              const float* __restrict__ sq,
                                              const float* __restrict__ sk,
                                              ushort* __restrict__ attn_bf) {
    int t = threadIdx.x;
    int i = blockIdx.x;
    int b = blockIdx.y;
    __shared__ float sqv_s[RR];
    __shared__ float redmax[4];
    __shared__ float redsum[4];
    __shared__ float bc_max;
    __shared__ float bc_sum;
    if (t < RR) sqv_s[t] = sq[((size_t)b * NN + i) * RR + t];
    __syncthreads();
    float sv[RR];
#pragma unroll
    for (int r = 0; r < RR; ++r) sv[r] = sqv_s[r];

    float z[2];
#pragma unroll
    for (int jj = 0; jj < 2; ++jj) {
        int j = t + jj * 256;
        size_t base = ((size_t)(b * NN + i) * NN + j) * RR;
        const int4* ap = reinterpret_cast<const int4*>(adj + base);
        int4 a0 = ap[0], a1 = ap[1], a2 = ap[2], a3 = ap[3];
        const float4* kp = reinterpret_cast<const float4*>(sk + ((size_t)b * NN + j) * RR);
        float4 s0 = kp[0], s1 = kp[1], s2 = kp[2], s3 = kp[3];
        int sum_adj = a0.x + a0.y + a0.z + a0.w + a1.x + a1.y + a1.z + a1.w +
                      a2.x + a2.y + a2.z + a2.w + a3.x + a3.y + a3.z + a3.w;
        float ssum = 0.f;
#define LR_TERM(SVAL, AVAL, RIDX)                                   \
        { float v_ = sv[RIDX] + (SVAL);                             \
          v_ = fmaxf(v_, 0.2f * v_);                                \
          ssum = fmaf(v_, (float)(AVAL), ssum); }
        LR_TERM(s0.x, a0.x, 0)  LR_TERM(s0.y, a0.y, 1)
        LR_TERM(s0.z, a0.z, 2)  LR_TERM(s0.w, a0.w, 3)
        LR_TERM(s1.x, a1.x, 4)  LR_TERM(s1.y, a1.y, 5)
        LR_TERM(s1.z, a1.z, 6)  LR_TERM(s1.w, a1.w, 7)
        LR_TERM(s2.x, a2.x, 8)  LR_TERM(s2.y, a2.y, 9)
        LR_TERM(s2.z, a2.z, 10) LR_TERM(s2.w, a2.w, 11)
        LR_TERM(s3.x, a3.x, 12) LR_TERM(s3.y, a3.y, 13)
        LR_TERM(s3.z, a3.z, 14) LR_TERM(s3.w, a3.w, 15)
#undef LR_TERM
        z[jj] = (sum_adj > 0) ? ssum : -9e15f;
    }

    int wv = t >> 6, ln = t & 63;
    float lm = fmaxf(z[0], z[1]);
    for (int off = 32; off; off >>= 1) lm = fmaxf(lm, __shfl_xor(lm, off, 64));
    if (ln == 0) redmax[wv] = lm;
    __syncthreads();
    if (t == 0) bc_max = fmaxf(fmaxf(redmax[0], redmax[1]), fmaxf(redmax[2], redmax[3]));
    __syncthreads();
    float mx = bc_max;
    float e0 = __expf(z[0] - mx);
    float e1 = __expf(z[1] - mx);
    float ls = e0 + e1;
    for (int off = 32; off; off >>= 1) ls += __shfl_xor(ls, off, 64);
    if (ln == 0) redsum[wv] = ls;
    __syncthreads();
    if (t == 0) bc_sum = redsum[0] + redsum[1] + redsum[2] + redsum[3];
    __syncthreads();
    float inv = 1.f / bc_sum;
    ushort* outp = attn_bf + (size_t)(b * NN + i) * NN;
    outp[t] = bf16_bits(e0 * inv);
    outp[t + 256] = bf16_bits(e1 * inv);
}

// ---------------------------------------------------------------------------
// bf16 MFMA GEMM: C[b] (MxN) = A[b] (MxK row-major, split at k=512) @ BT^T
// 64x64 tile; two BK=32 stages per barrier-pair (dual LDS buffers).
// grid (N/64, M/64, 8), block 256 = 4 waves
// ---------------------------------------------------------------------------
__global__ __launch_bounds__(256) void k_gemm(const ushort* __restrict__ A1, size_t sA1,
                                              const ushort* __restrict__ A2, size_t sA2,
                                              const ushort* __restrict__ BT, size_t sBT,
                                              float* __restrict__ Cf,
                                              ushort* __restrict__ Cb, size_t sC,
                                              int K, int ldBT) {
    __shared__ ushort As[2][64 * 40];  // stride 40 ushort = 80 B (16B-aligned rows)
    __shared__ ushort Bs[2][64 * 40];
    int t = threadIdx.x;
    int n0 = blockIdx.x * 64, m0 = blockIdx.y * 64, b = blockIdx.z;
    int row = t >> 2, c8 = (t & 3) * 8;
    int lane = t & 63, w = t >> 6;
    int m_l = lane & 15, q = lane >> 4;
    f32x4 acc[4] = {{0.f,0.f,0.f,0.f},{0.f,0.f,0.f,0.f},{0.f,0.f,0.f,0.f},{0.f,0.f,0.f,0.f}};
    const ushort* BTb = BT + (size_t)b * sBT;
    for (int k0 = 0; k0 < K; k0 += 64) {
#pragma unroll
        for (int h = 0; h < 2; ++h) {
            int kk = k0 + h * 32;
            const ushort* Aab; int kc;
            if (kk < FF) { Aab = A1 + (size_t)b * sA1; kc = kk; }
            else         { Aab = A2 + (size_t)b * sA2; kc = kk - FF; }
            uint4 av = *(const uint4*)(Aab + (size_t)(m0 + row) * FF + kc + c8);
            uint4 bv = *(const uint4*)(BTb + (size_t)(n0 + row) * ldBT + kk + c8);
            *(uint4*)(&As[h][row * 40 + c8]) = av;
            *(uint4*)(&Bs[h][row * 40 + c8]) = bv;
        }
        __syncthreads();
#pragma unroll
        for (int h = 0; h < 2; ++h) {
            short8 af = *(const short8*)(&As[h][(w * 16 + m_l) * 40 + q * 8]);
#pragma unroll
            for (int nb = 0; nb < 4; ++nb) {
                short8 bfr = *(const short8*)(&Bs[h][(nb * 16 + m_l) * 40 + q * 8]);
                acc[nb] = __builtin_amdgcn_mfma_f32_16x16x32_bf16(af, bfr, acc[nb], 0, 0, 0);
            }
        }
        __syncthreads();
    }
#pragma unroll
    for (int nb = 0; nb < 4; ++nb) {
#pragma unroll
        for (int r = 0; r < 4; ++r) {
            int mi = m0 + w * 16 + q * 4 + r;
            int ni = n0 + nb * 16 + m_l;
            float v = acc[nb][r];
            if (Cb) Cb[(size_t)b * sC + (size_t)mi * FF + ni] = bf16_bits(v);
            else    Cf[(size_t)b * sC + (size_t)mi * FF + ni] = v;
        }
    }
}

// ---------------------------------------------------------------------------
// Launch
// ---------------------------------------------------------------------------
extern "C" void kernel_launch(void* const* d_in, const int* in_sizes, int n_in,
                              void* d_out, int out_size, void* d_ws, size_t ws_size,
                              hipStream_t stream) {
    const float* x_ori = (const float*)d_in[0];
    const float* x     = (const float*)d_in[1];
    const float* c     = (const float*)d_in[2];
    const int*   adj   = (const int*)d_in[3];
    const float* Wfc   = (const float*)d_in[4];
    const float* Wdc   = (const float*)d_in[5];
    const float* Wqv   = (const float*)d_in[6];
    const float* Wkv   = (const float*)d_in[7];
    const float* Wqc   = (const float*)d_in[8];
    const float* Wkc   = (const float*)d_in[9];
    const float* Wa    = (const float*)d_in[10];
    const float* Wu    = (const float*)d_in[11];
    float* out = (float*)d_out;

    char* ws = (char*)d_ws;
    float*  tb      = (float*)(ws + OFF_TB);
    float*  mb      = (float*)(ws + OFF_MB);
    float*  mq      = (float*)(ws + OFF_MQ);
    float*  mk      = (float*)(ws + OFF_MK);
    float*  sq      = (float*)(ws + OFF_SQ);
    float*  sk      = (float*)(ws + OFF_SK);
    ushort* WqEt    = (ushort*)(ws + OFF_WQET);
    ushort* WkEt    = (ushort*)(ws + OFF_WKET);
    ushort* attn_bf = (ushort*)(ws + OFF_ATTN);
    ushort* x_bf    = (ushort*)(ws + OFF_XBF);
    ushort* xT_bf   = (ushort*)(ws + OFF_XTBF);
    ushort* xori_bf = (ushort*)(ws + OFF_XORIBF);
    ushort* newx_bf = (ushort*)(ws + OFF_NEWXBF);
    ushort* WuT     = (ushort*)(ws + OFF_WUT);

    dim3 blk(256);

    // 1) conversions/transposes (uniform parallelism only)
    k_prep<<<dim3(3584), blk, 0, stream>>>(x_ori, x, Wu, xori_bf, x_bf, xT_bf, WuT);

    // 2) m-chain: 3 small wide GEMV launches (128 blocks each)
    k_matvec<<<dim3(16, BSZ), blk, 0, stream>>>(c, Wfc, tb, 1);
    k_matvec<<<dim3(16, BSZ), blk, 0, stream>>>(tb, Wdc, mb, 0);
    k_mqk<<<dim3(16, BSZ), blk, 0, stream>>>(mb, Wqc, Wkc, mq, mk);

    // 3) effective low-rank weights (q and k via blockIdx.z)
    k_weff<<<dim3(16, BSZ, 2), blk, 0, stream>>>(Wqv, Wkv, Wa, mq, mk, WqEt, WkEt);

    // 4) sq / sk via LDS-free MFMA
    k_sqsk<<<dim3(16, BSZ), blk, 0, stream>>>(x_bf, xori_bf, WqEt, WkEt, sq, sk);

    // 5) scores + mask + softmax -> attn (bf16)
    k_attn<<<dim3(NN, BSZ), blk, 0, stream>>>(adj, sq, sk, attn_bf);

    // 6) new_x = attn @ x
    k_gemm<<<dim3(8, 8, BSZ), blk, 0, stream>>>(
        attn_bf, (size_t)NN * NN, attn_bf, (size_t)NN * NN,
        xT_bf, (size_t)FF * NN, nullptr, newx_bf, (size_t)NN * FF, FF, NN);

    // 7) out = [x | new_x] @ Wu
    k_gemm<<<dim3(8, 8, BSZ), blk, 0, stream>>>(
        x_bf, (size_t)NN * FF, newx_bf, (size_t)NN * FF,
        WuT, (size_t)0, out, nullptr, (size_t)NN * FF, TWOF, TWOF);
}

// Round 5
// 302.944 us; speedup vs baseline: 1.5938x; 1.0172x over previous
//
#include <hip/hip_runtime.h>
#include <hip/hip_bf16.h>
#include <cstddef>
#include <cstdint>

static constexpr int BSZ  = 8;
static constexpr int NN   = 512;
static constexpr int FF   = 512;
static constexpr int RR   = 16;
static constexpr int TWOF = 1024;

typedef __attribute__((ext_vector_type(8))) short short8;   // 8 bf16 in 4 VGPRs
typedef __attribute__((ext_vector_type(4))) float f32x4;

__device__ __forceinline__ ushort bf16_bits(float v) {
    union { __hip_bfloat16 h; ushort u; } cvt;
    cvt.h = __float2bfloat16(v);
    return cvt.u;
}

// ---------------------------------------------------------------------------
// Workspace layout (byte offsets, 256B aligned)
// ---------------------------------------------------------------------------
static constexpr size_t OFF_TB     = 0;         // f32 [8][512]
static constexpr size_t OFF_MB     = 16384;     // f32 [8][512]
static constexpr size_t OFF_MQ     = 32768;     // f32 [8][512]
static constexpr size_t OFF_MK     = 49152;     // f32 [8][512]
static constexpr size_t OFF_SQ     = 65536;     // f32 [8][512][16]
static constexpr size_t OFF_SK     = 327680;    // f32 [8][512][16]
static constexpr size_t OFF_WQET   = 589824;    // bf16 [8][16][1024]
static constexpr size_t OFF_WKET   = 851968;    // bf16 [8][16][1024]
static constexpr size_t OFF_XBF    = 5308416;   // bf16 [8][512][512]
static constexpr size_t OFF_XTBF   = 9502720;   // bf16 [8][512][512]  (x^T per b)
static constexpr size_t OFF_XORIBF = 13697024;  // bf16 [8][512][512]
static constexpr size_t OFF_NEWXBF = 17891328;  // bf16 [8][512][512]
static constexpr size_t OFF_WUT    = 22085632;  // bf16 [512][1024]    (Wu^T)

// ---------------------------------------------------------------------------
// Fused prep kernel (uniform-magnitude branches only — each branch 1-6 µs):
//   blocks [0,1024):     x_ori -> xori_bf
//   blocks [1024,3072):  x -> x_bf + xT_bf (32x32 transpose tiles)
//   blocks [3072,3584):  Wu -> WuT_bf
//   blocks [3584,3712):  m-chain stage1: tb = elu(c @ Wfc)  (128-block GEMV)
// ---------------------------------------------------------------------------
__global__ __launch_bounds__(256) void k_prep(
    const float* __restrict__ x_ori, const float* __restrict__ x,
    const float* __restrict__ c, const float* __restrict__ Wfc,
    const float* __restrict__ Wu,
    ushort* __restrict__ xori_bf, ushort* __restrict__ x_bf,
    ushort* __restrict__ xT_bf, ushort* __restrict__ WuT,
    float* __restrict__ tb)
{
    int blk = blockIdx.x;
    int t = threadIdx.x;
    if (blk < 1024) {
        int idx = blk * 256 + t;
        float4 a = ((const float4*)x_ori)[idx * 2];
        float4 b = ((const float4*)x_ori)[idx * 2 + 1];
        uint4 s;
        s.x = (uint)bf16_bits(a.x) | ((uint)bf16_bits(a.y) << 16);
        s.y = (uint)bf16_bits(a.z) | ((uint)bf16_bits(a.w) << 16);
        s.z = (uint)bf16_bits(b.x) | ((uint)bf16_bits(b.y) << 16);
        s.w = (uint)bf16_bits(b.z) | ((uint)bf16_bits(b.w) << 16);
        ((uint4*)xori_bf)[idx] = s;
    } else if (blk < 3072) {
        __shared__ float tile[32][33];
        int bb = blk - 1024;
        int f0 = (bb & 15) * 32, i0 = ((bb >> 4) & 15) * 32, b = bb >> 8;
        int cc = t & 31, r0 = t >> 5;  // r0 in 0..7
#pragma unroll
        for (int rr = 0; rr < 32; rr += 8) {
            int i = i0 + r0 + rr;
            float v = x[((size_t)b * NN + i) * FF + f0 + cc];
            tile[r0 + rr][cc] = v;
            x_bf[((size_t)b * NN + i) * FF + f0 + cc] = bf16_bits(v);
        }
        __syncthreads();
#pragma unroll
        for (int rr = 0; rr < 32; rr += 8) {
            int f = f0 + r0 + rr;
            xT_bf[((size_t)b * FF + f) * NN + i0 + cc] = bf16_bits(tile[cc][r0 + rr]);
        }
    } else if (blk < 3584) {
        __shared__ float tile2[32][33];
        int bb = blk - 3072;
        int f0 = (bb & 31) * 32, o0 = (bb >> 5) * 32;
        int cc = t & 31, r0 = t >> 5;
#pragma unroll
        for (int rr = 0; rr < 32; rr += 8)
            tile2[r0 + rr][cc] = Wu[(size_t)(f0 + r0 + rr) * FF + o0 + cc];
        __syncthreads();
#pragma unroll
        for (int rr = 0; rr < 32; rr += 8)
            WuT[(size_t)(o0 + r0 + rr) * TWOF + f0 + cc] = bf16_bits(tile2[cc][r0 + rr]);
    } else {
        // m-chain stage 1: tb = elu(c @ Wfc), grid-equivalent (16,8)
        __shared__ float red1[8][32];
        int bb = blk - 3584;
        int b = bb >> 4, f0 = (bb & 15) * 32;
        int f = t & 31, kq = t >> 5;
        const float* vb = c + (size_t)b * FF;
        float acc = 0.f;
        int ks = kq * 64;
#pragma unroll 8
        for (int k = ks; k < ks + 64; ++k)
            acc = fmaf(vb[k], Wfc[(size_t)k * FF + f0 + f], acc);
        red1[kq][f] = acc;
        __syncthreads();
        if (kq == 0) {
            acc += red1[1][f] + red1[2][f] + red1[3][f] + red1[4][f] +
                   red1[5][f] + red1[6][f] + red1[7][f];
            tb[(size_t)b * FF + f0 + f] = (acc > 0.f) ? acc : expm1f(acc);
        }
    }
}

// ---------------------------------------------------------------------------
// Batched GEMV: vout[b,f] = vin[b,:] @ W[:,f]
// grid (16 fb, 8 b), block 256 = (32 f, 8 kq)
// ---------------------------------------------------------------------------
__global__ __launch_bounds__(256) void k_matvec(const float* __restrict__ vin,
                                                const float* __restrict__ W,
                                                float* __restrict__ vout) {
    __shared__ float red[8][32];
    int b = blockIdx.y;
    int f0 = blockIdx.x * 32;
    int t = threadIdx.x;
    int f = t & 31, kq = t >> 5;
    const float* vb = vin + (size_t)b * FF;
    float acc = 0.f;
    int ks = kq * 64;
#pragma unroll 8
    for (int k = ks; k < ks + 64; ++k)
        acc = fmaf(vb[k], W[(size_t)k * FF + f0 + f], acc);
    red[kq][f] = acc;
    __syncthreads();
    if (kq == 0) {
        acc += red[1][f] + red[2][f] + red[3][f] + red[4][f] +
               red[5][f] + red[6][f] + red[7][f];
        vout[(size_t)b * FF + f0 + f] = acc;
    }
}

// mq = m @ Wqc ; mk = m @ Wkc
__global__ __launch_bounds__(256) void k_mqk(const float* __restrict__ m,
                                             const float* __restrict__ Wqc,
                                             const float* __restrict__ Wkc,
                                             float* __restrict__ mq,
                                             float* __restrict__ mk) {
    __shared__ float redq[8][32];
    __shared__ float redk[8][32];
    int b = blockIdx.y;
    int f0 = blockIdx.x * 32;
    int t = threadIdx.x;
    int f = t & 31, kq = t >> 5;
    const float* mb = m + (size_t)b * FF;
    float aq = 0.f, ak = 0.f;
    int ks = kq * 64;
#pragma unroll 8
    for (int k = ks; k < ks + 64; ++k) {
        float mv = mb[k];
        aq = fmaf(mv, Wqc[(size_t)k * FF + f0 + f], aq);
        ak = fmaf(mv, Wkc[(size_t)k * FF + f0 + f], ak);
    }
    redq[kq][f] = aq;
    redk[kq][f] = ak;
    __syncthreads();
    if (kq == 0) {
        aq += redq[1][f] + redq[2][f] + redq[3][f] + redq[4][f] +
              redq[5][f] + redq[6][f] + redq[7][f];
        ak += redk[1][f] + redk[2][f] + redk[3][f] + redk[4][f] +
              redk[5][f] + redk[6][f] + redk[7][f];
        mq[(size_t)b * FF + f0 + f] = aq;
        mk[(size_t)b * FF + f0 + f] = ak;
    }
}

// ---------------------------------------------------------------------------
// W_eff^T[b,r,k] = sum_f W[k,f] * mvec[b,f] * Wa[waRowOff+f, r]  (bf16 out)
// grid (16 kchunks, 8 b, 2 {q,k}), block 256.  f-loop vectorized x4.
// ---------------------------------------------------------------------------
__global__ __launch_bounds__(256) void k_weff(const float* __restrict__ Wqv,
                                              const float* __restrict__ Wkv,
                                              const float* __restrict__ Wa,
                                              const float* __restrict__ mqv,
                                              const float* __restrict__ mkv,
                                              ushort* __restrict__ WqEt,
                                              ushort* __restrict__ WkEt) {
    int z = blockIdx.z;
    const float* W = z ? Wkv : Wqv;
    const float* mvec = z ? mkv : mqv;
    ushort* WeffT = z ? WkEt : WqEt;
    int waRowOff = z ? FF : 0;

    __shared__ float4 wa4[FF * 4];  // [f][r4] scaled Wa, 32 KiB
    int tid = threadIdx.x;
    int b = blockIdx.y;
    const float* mv = mvec + (size_t)b * FF;
#pragma unroll
    for (int qq = 0; qq < 8; ++qq) {
        int idx = tid + qq * 256;
        int f = idx >> 2, rq = idx & 3;
        float4 w = *reinterpret_cast<const float4*>(Wa + (size_t)(waRowOff + f) * RR + rq * 4);
        float s = mv[f];
        float4 o;
        o.x = w.x * s; o.y = w.y * s; o.z = w.z * s; o.w = w.w * s;
        wa4[idx] = o;
    }
    __syncthreads();
    int k_l = tid >> 2, r4 = tid & 3;
    int k = blockIdx.x * 64 + k_l;
    const float4* Wrow4 = reinterpret_cast<const float4*>(W + (size_t)k * FF);
    float4 acc = {0.f, 0.f, 0.f, 0.f};
#pragma unroll 4
    for (int f4 = 0; f4 < FF / 4; ++f4) {
        float4 w = Wrow4[f4];
        float4 v0 = wa4[(f4 * 4 + 0) * 4 + r4];
        float4 v1 = wa4[(f4 * 4 + 1) * 4 + r4];
        float4 v2 = wa4[(f4 * 4 + 2) * 4 + r4];
        float4 v3 = wa4[(f4 * 4 + 3) * 4 + r4];
        acc.x = fmaf(w.x, v0.x, acc.x); acc.y = fmaf(w.x, v0.y, acc.y);
        acc.z = fmaf(w.x, v0.z, acc.z); acc.w = fmaf(w.x, v0.w, acc.w);
        acc.x = fmaf(w.y, v1.x, acc.x); acc.y = fmaf(w.y, v1.y, acc.y);
        acc.z = fmaf(w.y, v1.z, acc.z); acc.w = fmaf(w.y, v1.w, acc.w);
        acc.x = fmaf(w.z, v2.x, acc.x); acc.y = fmaf(w.z, v2.y, acc.y);
        acc.z = fmaf(w.z, v2.z, acc.z); acc.w = fmaf(w.z, v2.w, acc.w);
        acc.x = fmaf(w.w, v3.x, acc.x); acc.y = fmaf(w.w, v3.y, acc.y);
        acc.z = fmaf(w.w, v3.z, acc.z); acc.w = fmaf(w.w, v3.w, acc.w);
    }
    WeffT[((size_t)b * RR + r4 * 4 + 0) * TWOF + k] = bf16_bits(acc.x);
    WeffT[((size_t)b * RR + r4 * 4 + 1) * TWOF + k] = bf16_bits(acc.y);
    WeffT[((size_t)b * RR + r4 * 4 + 2) * TWOF + k] = bf16_bits(acc.z);
    WeffT[((size_t)b * RR + r4 * 4 + 3) * TWOF + k] = bf16_bits(acc.w);
}

// ---------------------------------------------------------------------------
// sq/sk via MFMA, LDS-free. grid (16 m-tiles of 32, 8 b), block 256 = 4 waves
// ---------------------------------------------------------------------------
__global__ __launch_bounds__(256) void k_sqsk(const ushort* __restrict__ x_bf,
                                              const ushort* __restrict__ xori_bf,
                                              const ushort* __restrict__ WqEt,
                                              const ushort* __restrict__ WkEt,
                                              float* __restrict__ sq,
                                              float* __restrict__ sk) {
    int t = threadIdx.x;
    int b = blockIdx.y;
    int m0 = blockIdx.x * 32;
    int lane = t & 63, w = t >> 6;
    int sub = w & 1, isK = w >> 1;
    int m_l = lane & 15, q = lane >> 4;
    int row = m0 + sub * 16 + m_l;
    const ushort* Bt = (isK ? WkEt : WqEt) + ((size_t)b * RR + m_l) * TWOF;
    f32x4 acc = {0.f, 0.f, 0.f, 0.f};
#pragma unroll
    for (int k0 = 0; k0 < TWOF; k0 += 32) {
        const ushort* src = (k0 < FF) ? x_bf : xori_bf;
        int kc = k0 & (FF - 1);
        short8 af = *(const short8*)(src + ((size_t)b * NN + row) * FF + kc + q * 8);
        short8 bf = *(const short8*)(Bt + k0 + q * 8);
        acc = __builtin_amdgcn_mfma_f32_16x16x32_bf16(af, bf, acc, 0, 0, 0);
    }
    float* dst = isK ? sk : sq;
#pragma unroll
    for (int r = 0; r < 4; ++r) {
        int i = m0 + sub * 16 + q * 4 + r;
        dst[((size_t)b * NN + i) * RR + m_l] = acc[r];
    }
}

// ---------------------------------------------------------------------------
// Fused scores + softmax + PV (flash-style): newx[b, m0..m0+16, :] directly.
// grid (32 i-tiles of 16, 8 b), block 256 (4 waves).
//   Phase A: z[16][512] into LDS (adj-read HBM-bound — the kernel's floor)
//   Phase B: row max/sum; P = bf16(exp(z-max)) in LDS (1/sum folded into C)
//   Phase C: newx = P @ x via MFMA; A-frag from LDS-P, B-frag = 16-B global
//            loads from L2-hot xT_bf; epilogue scales by 1/rowsum.
// LDS: 50 KB. PV compute (~128 MFMA/wave) hides under phase-A HBM stream.
// ---------------------------------------------------------------------------
__global__ __launch_bounds__(256) void k_attn_pv(const int* __restrict__ adj,
                                                 const float* __restrict__ sq,
                                                 const float* __restrict__ sk,
                                                 const ushort* __restrict__ xT_bf,
                                                 ushort* __restrict__ newx_bf) {
    constexpr int ZS = 520;            // padded row stride (words / ushorts)
    __shared__ float  zbuf[16 * ZS];   // 33.3 KB
    __shared__ ushort P[16 * ZS];      // 16.6 KB
    __shared__ float  rowsum[16];
    int t = threadIdx.x;
    int b = blockIdx.y;
    int m0 = blockIdx.x * 16;

    // ---- Phase A: scores ----
    {
        int r = t >> 4, cc = t & 15;
        int i = m0 + r;
        const float4* sqp = (const float4*)(sq + ((size_t)b * NN + i) * RR);
        float4 q0 = sqp[0], q1 = sqp[1], q2 = sqp[2], q3 = sqp[3];
        float sv[16] = {q0.x, q0.y, q0.z, q0.w, q1.x, q1.y, q1.z, q1.w,
                        q2.x, q2.y, q2.z, q2.w, q3.x, q3.y, q3.z, q3.w};
#pragma unroll 4
        for (int it = 0; it < 32; ++it) {
            int j = it * 16 + cc;
            size_t base = (((size_t)b * NN + i) * NN + j) * RR;
            const int4* ap = (const int4*)(adj + base);
            int4 a0 = ap[0], a1 = ap[1], a2 = ap[2], a3 = ap[3];
            const float4* kp = (const float4*)(sk + ((size_t)b * NN + j) * RR);
            float4 s0 = kp[0], s1 = kp[1], s2 = kp[2], s3 = kp[3];
            int sum_adj = a0.x + a0.y + a0.z + a0.w + a1.x + a1.y + a1.z + a1.w +
                          a2.x + a2.y + a2.z + a2.w + a3.x + a3.y + a3.z + a3.w;
            float ssum = 0.f;
#define LR_TERM(SVAL, AVAL, RIDX)                                   \
            { float v_ = sv[RIDX] + (SVAL);                         \
              v_ = fmaxf(v_, 0.2f * v_);                            \
              ssum = fmaf(v_, (float)(AVAL), ssum); }
            LR_TERM(s0.x, a0.x, 0)  LR_TERM(s0.y, a0.y, 1)
            LR_TERM(s0.z, a0.z, 2)  LR_TERM(s0.w, a0.w, 3)
            LR_TERM(s1.x, a1.x, 4)  LR_TERM(s1.y, a1.y, 5)
            LR_TERM(s1.z, a1.z, 6)  LR_TERM(s1.w, a1.w, 7)
            LR_TERM(s2.x, a2.x, 8)  LR_TERM(s2.y, a2.y, 9)
            LR_TERM(s2.z, a2.z, 10) LR_TERM(s2.w, a2.w, 11)
            LR_TERM(s3.x, a3.x, 12) LR_TERM(s3.y, a3.y, 13)
            LR_TERM(s3.z, a3.z, 14) LR_TERM(s3.w, a3.w, 15)
#undef LR_TERM
            zbuf[r * ZS + j] = (sum_adj > 0) ? ssum : -9e15f;
        }
    }
    __syncthreads();

    // ---- Phase B: row softmax (unnormalized e into P) ----
    {
        int w = t >> 6, lane = t & 63;
        int rr = w * 4 + (lane >> 4);   // row 0..15
        int cc = lane & 15;
        const float* zr = &zbuf[rr * ZS];
        float mx = -3.0e38f;
#pragma unroll 8
        for (int it = 0; it < 32; ++it) mx = fmaxf(mx, zr[it * 16 + cc]);
#pragma unroll
        for (int off = 1; off < 16; off <<= 1) mx = fmaxf(mx, __shfl_xor(mx, off, 64));
        float sum = 0.f;
        ushort* pr = &P[rr * ZS];
#pragma unroll 8
        for (int it = 0; it < 32; ++it) {
            float e = __expf(zr[it * 16 + cc] - mx);
            pr[it * 16 + cc] = bf16_bits(e);
            sum += e;
        }
#pragma unroll
        for (int off = 1; off < 16; off <<= 1) sum += __shfl_xor(sum, off, 64);
        if (cc == 0) rowsum[rr] = sum;
    }
    __syncthreads();

    // ---- Phase C: newx tile = P(16x512) @ x(512x512) via MFMA ----
    {
        int w = t >> 6, lane = t & 63;
        int m_l = lane & 15, q = lane >> 4;
        int n0w = w * 128;
        f32x4 acc[8] = {};
        const ushort* xTb = xT_bf + (size_t)b * FF * NN;
        for (int k0 = 0; k0 < NN; k0 += 32) {
            short8 af = *(const short8*)(&P[m_l * ZS + k0 + q * 8]);
#pragma unroll
            for (int nb = 0; nb < 8; ++nb) {
                int n = n0w + nb * 16 + m_l;
                short8 bfr = *(const short8*)(xTb + (size_t)n * NN + k0 + q * 8);
                acc[nb] = __builtin_amdgcn_mfma_f32_16x16x32_bf16(af, bfr, acc[nb], 0, 0, 0);
            }
        }
        float inv[4];
#pragma unroll
        for (int rg = 0; rg < 4; ++rg) inv[rg] = 1.f / rowsum[q * 4 + rg];
#pragma unroll
        for (int nb = 0; nb < 8; ++nb) {
#pragma unroll
            for (int rg = 0; rg < 4; ++rg) {
                int i = m0 + q * 4 + rg;
                int f = n0w + nb * 16 + m_l;
                newx_bf[((size_t)b * NN + i) * FF + f] = bf16_bits(acc[nb][rg] * inv[rg]);
            }
        }
    }
}

// ---------------------------------------------------------------------------
// bf16 MFMA GEMM: C[b] (MxN) = A[b] (MxK row-major, split at k=512) @ BT^T
// 64x64 tile; two BK=32 stages per barrier-pair. grid (N/64, M/64, 8)
// ---------------------------------------------------------------------------
__global__ __launch_bounds__(256) void k_gemm(const ushort* __restrict__ A1, size_t sA1,
                                              const ushort* __restrict__ A2, size_t sA2,
                                              const ushort* __restrict__ BT, size_t sBT,
                                              float* __restrict__ Cf, size_t sC,
                                              int K, int ldBT) {
    __shared__ ushort As[2][64 * 40];  // stride 40 ushort = 80 B (16B-aligned rows)
    __shared__ ushort Bs[2][64 * 40];
    int t = threadIdx.x;
    int n0 = blockIdx.x * 64, m0 = blockIdx.y * 64, b = blockIdx.z;
    int row = t >> 2, c8 = (t & 3) * 8;
    int lane = t & 63, w = t >> 6;
    int m_l = lane & 15, q = lane >> 4;
    f32x4 acc[4] = {{0.f,0.f,0.f,0.f},{0.f,0.f,0.f,0.f},{0.f,0.f,0.f,0.f},{0.f,0.f,0.f,0.f}};
    const ushort* BTb = BT + (size_t)b * sBT;
    for (int k0 = 0; k0 < K; k0 += 64) {
#pragma unroll
        for (int h = 0; h < 2; ++h) {
            int kk = k0 + h * 32;
            const ushort* Aab; int kc;
            if (kk < FF) { Aab = A1 + (size_t)b * sA1; kc = kk; }
            else         { Aab = A2 + (size_t)b * sA2; kc = kk - FF; }
            uint4 av = *(const uint4*)(Aab + (size_t)(m0 + row) * FF + kc + c8);
            uint4 bv = *(const uint4*)(BTb + (size_t)(n0 + row) * ldBT + kk + c8);
            *(uint4*)(&As[h][row * 40 + c8]) = av;
            *(uint4*)(&Bs[h][row * 40 + c8]) = bv;
        }
        __syncthreads();
#pragma unroll
        for (int h = 0; h < 2; ++h) {
            short8 af = *(const short8*)(&As[h][(w * 16 + m_l) * 40 + q * 8]);
#pragma unroll
            for (int nb = 0; nb < 4; ++nb) {
                short8 bfr = *(const short8*)(&Bs[h][(nb * 16 + m_l) * 40 + q * 8]);
                acc[nb] = __builtin_amdgcn_mfma_f32_16x16x32_bf16(af, bfr, acc[nb], 0, 0, 0);
            }
        }
        __syncthreads();
    }
#pragma unroll
    for (int nb = 0; nb < 4; ++nb) {
#pragma unroll
        for (int r = 0; r < 4; ++r) {
            int mi = m0 + w * 16 + q * 4 + r;
            int ni = n0 + nb * 16 + m_l;
            Cf[(size_t)b * sC + (size_t)mi * FF + ni] = acc[nb][r];
        }
    }
}

// ---------------------------------------------------------------------------
// Launch
// ---------------------------------------------------------------------------
extern "C" void kernel_launch(void* const* d_in, const int* in_sizes, int n_in,
                              void* d_out, int out_size, void* d_ws, size_t ws_size,
                              hipStream_t stream) {
    const float* x_ori = (const float*)d_in[0];
    const float* x     = (const float*)d_in[1];
    const float* c     = (const float*)d_in[2];
    const int*   adj   = (const int*)d_in[3];
    const float* Wfc   = (const float*)d_in[4];
    const float* Wdc   = (const float*)d_in[5];
    const float* Wqv   = (const float*)d_in[6];
    const float* Wkv   = (const float*)d_in[7];
    const float* Wqc   = (const float*)d_in[8];
    const float* Wkc   = (const float*)d_in[9];
    const float* Wa    = (const float*)d_in[10];
    const float* Wu    = (const float*)d_in[11];
    float* out = (float*)d_out;

    char* ws = (char*)d_ws;
    float*  tb      = (float*)(ws + OFF_TB);
    float*  mb      = (float*)(ws + OFF_MB);
    float*  mq      = (float*)(ws + OFF_MQ);
    float*  mk      = (float*)(ws + OFF_MK);
    float*  sq      = (float*)(ws + OFF_SQ);
    float*  sk      = (float*)(ws + OFF_SK);
    ushort* WqEt    = (ushort*)(ws + OFF_WQET);
    ushort* WkEt    = (ushort*)(ws + OFF_WKET);
    ushort* x_bf    = (ushort*)(ws + OFF_XBF);
    ushort* xT_bf   = (ushort*)(ws + OFF_XTBF);
    ushort* xori_bf = (ushort*)(ws + OFF_XORIBF);
    ushort* newx_bf = (ushort*)(ws + OFF_NEWXBF);
    ushort* WuT     = (ushort*)(ws + OFF_WUT);

    dim3 blk(256);

    // 1) conversions/transposes + m-chain stage 1
    k_prep<<<dim3(3712), blk, 0, stream>>>(x_ori, x, c, Wfc, Wu,
                                           xori_bf, x_bf, xT_bf, WuT, tb);

    // 2) m-chain stages 2-3
    k_matvec<<<dim3(16, BSZ), blk, 0, stream>>>(tb, Wdc, mb);
    k_mqk<<<dim3(16, BSZ), blk, 0, stream>>>(mb, Wqc, Wkc, mq, mk);

    // 3) effective low-rank weights (q and k via blockIdx.z)
    k_weff<<<dim3(16, BSZ, 2), blk, 0, stream>>>(Wqv, Wkv, Wa, mq, mk, WqEt, WkEt);

    // 4) sq / sk via LDS-free MFMA
    k_sqsk<<<dim3(16, BSZ), blk, 0, stream>>>(x_bf, xori_bf, WqEt, WkEt, sq, sk);

    // 5) scores + softmax + PV fused -> newx (bf16)
    k_attn_pv<<<dim3(32, BSZ), blk, 0, stream>>>(adj, sq, sk, xT_bf, newx_bf);

    // 6) out = [x | new_x] @ Wu
    k_gemm<<<dim3(8, 8, BSZ), blk, 0, stream>>>(
        x_bf, (size_t)NN * FF, newx_bf, (size_t)NN * FF,
        WuT, (size_t)0, out, (size_t)NN * FF, TWOF, TWOF);
}